// Round 1
// baseline (2020.557 us; speedup 1.0000x reference)
//
#include <hip/hip_runtime.h>
#include <math.h>

// Problem constants
#define NB   64
#define CIN  64
#define TDIM 256
#define VV   25
#define SS   3
#define COUT 128
#define CTOT 384
#define NTV  (NB * TDIM * VV)       // 409600 elements per channel for BN stats
#define OUT_TOTAL (NB * COUT * TDIM * VV)  // 52428800

// Workspace float offsets
#define WS_STATS 0        // 8 copies x (128 sum + 128 sumsq) = 2048 floats
#define WS_AE2   2048     // [25][84]: Aeff[s][v][w] laid out ae[v*84 + s*28 + w], w-pad zeros
#define WS_W2    4160     // [24][128]: W2[(s*8+j)*128 + c] = Wg[(s*128+c)*8 + j]
#define WS_BIAS  7232     // [128][28]: bias_eff[c][w] = sum_s bg[s*128+c]*colsum_Aeff[s][w]
#define WS_SCALE 10816    // [128]
#define WS_SHIFT 10944    // [128]
#define WS_TOTAL 11072    // floats (44.3 KB)

__device__ __forceinline__ void fma4(float4& a, float s, const float4& b) {
    a.x = fmaf(s, b.x, a.x);
    a.y = fmaf(s, b.y, a.y);
    a.z = fmaf(s, b.z, a.z);
    a.w = fmaf(s, b.w, a.w);
}

// ---------------------------------------------------------------------------
// Prep: build Aeff / W2 / bias_eff tables in ws, zero the stats accumulators.
// ---------------------------------------------------------------------------
__global__ void prep_kernel(const float* __restrict__ A, const float* __restrict__ PA,
                            const float* __restrict__ Wg, const float* __restrict__ bg,
                            float* __restrict__ ws) {
    const int tid = threadIdx.x;
    for (int i = tid; i < 2048; i += 256) ws[WS_STATS + i] = 0.0f;
    // Aeff: ae[v*84 + s*28 + w]
    for (int i = tid; i < 25 * 84; i += 256) {
        int v = i / 84, r = i % 84;
        int s = r / 28, w = r % 28;
        float val = 0.0f;
        if (w < 25) {
            int idx = s * 625 + v * 25 + w;
            val = A[idx] + PA[idx];
        }
        ws[WS_AE2 + i] = val;
    }
    // W2[(s*8+j)*128 + c] = Wg[(s*128+c)*8 + j]
    for (int i = tid; i < 24 * 128; i += 256) {
        int row = i / 128, c = i % 128;
        int s = row / 8, j = row % 8;
        ws[WS_W2 + i] = Wg[(s * 128 + c) * 8 + j];
    }
    // bias_eff[c][w] (w padded to 28)
    for (int i = tid; i < 128 * 28; i += 256) {
        int c = i / 28, w = i % 28;
        float val = 0.0f;
        if (w < 25) {
            for (int s = 0; s < 3; ++s) {
                float cs = 0.0f;
                for (int v = 0; v < 25; ++v) {
                    int idx = s * 625 + v * 25 + w;
                    cs += A[idx] + PA[idx];
                }
                val += bg[s * 128 + c] * cs;
            }
        }
        ws[WS_BIAS + i] = val;
    }
}

// ---------------------------------------------------------------------------
// Main: one block per (n,t). Adjacency-first then grouped conv (6.4 GFLOP
// total vs 10.4 for reference order). Writes unnormalized total to d_out and
// accumulates per-channel sum/sumsq into 8 striped global accumulators.
// ---------------------------------------------------------------------------
__global__ __launch_bounds__(256, 3)
void main_kernel(const float* __restrict__ x, float* __restrict__ ws,
                 float* __restrict__ out) {
    // LDS: 1700 + 2100 + 3072 + 5376 + 256 = 12504 floats = 50,016 B -> 3 blk/CU
    __shared__ __align__(16) float s_x[25 * 68];    // xst[v][cin], pad 68 (bank + b128 align)
    __shared__ __align__(16) float s_ae[25 * 84];   // ae[v][s*28+w]
    __shared__ __align__(16) float s_w[24 * 128];   // W2[(s*8+j)][c]
    __shared__ __align__(16) float s_y[3 * 64 * 28];// y[s][cin][w-pad28]; later aliased as res[128*25]
    __shared__ float s_stats[256];                  // 128 sum + 128 sumsq

    const int tid = threadIdx.x;
    const int bid = blockIdx.x;
    const int n = bid >> 8;     // 256 t per n
    const int t = bid & 255;

    s_stats[tid] = 0.0f;

    // Stage x[n,:,t,:] -> s_x[v*68 + cin]
    const float* xb = x + (size_t)n * (CIN * TDIM * VV) + t * VV;
    for (int i = tid; i < 64 * 25; i += 256) {
        int cin = i / 25, v = i % 25;
        s_x[v * 68 + cin] = xb[cin * (TDIM * VV) + v];
    }
    for (int i = tid; i < 25 * 84; i += 256) s_ae[i] = ws[WS_AE2 + i];
    for (int i = tid; i < 24 * 128; i += 256) s_w[i] = ws[WS_W2 + i];
    __syncthreads();

    // Stage 2: y[s][cin][w] = sum_v x[cin][v] * Aeff[s][v][w]
    // 336 tasks: 21 sw-tiles(4) x 16 cin-tiles(4), cin fastest (conflict-free reads)
    for (int task = tid; task < 336; task += 256) {
        int cint = task & 15, swt = task >> 4;
        int cin0 = cint * 4, sw0 = swt * 4;
        float4 a0 = {0, 0, 0, 0}, a1 = a0, a2 = a0, a3 = a0;
        #pragma unroll
        for (int v = 0; v < 25; ++v) {
            float4 xv = *(const float4*)&s_x[v * 68 + cin0];
            float4 av = *(const float4*)&s_ae[v * 84 + sw0];
            fma4(a0, xv.x, av);
            fma4(a1, xv.y, av);
            fma4(a2, xv.z, av);
            fma4(a3, xv.w, av);
        }
        int s = sw0 / 28, w0 = sw0 % 28;  // tiles never cross s (28 % 4 == 0)
        int yb = (s * 64 + cin0) * 28 + w0;
        *(float4*)&s_y[yb]      = a0;
        *(float4*)&s_y[yb + 28] = a1;
        *(float4*)&s_y[yb + 56] = a2;
        *(float4*)&s_y[yb + 84] = a3;
    }
    __syncthreads();

    // Stage 3: total[c][w] = bias_eff[c][w] + sum_s sum_j W2[s8+j][c]*y[s][g*8+j][w]
    // 224 tasks: 7 w-tiles(4) x 32 c-tiles(4), c fastest. g uniform within a
    // 4-aligned c-tile (g boundaries fall on multiples of 16).
    const bool active = tid < 224;
    int c0 = 0, w0 = 0;
    float4 r0, r1, r2, r3;
    if (active) {
        int ct = tid & 31, wt = tid >> 5;
        c0 = ct * 4;
        w0 = wt * 4;
        r0 = *(const float4*)&ws[WS_BIAS + (c0 + 0) * 28 + w0];
        r1 = *(const float4*)&ws[WS_BIAS + (c0 + 1) * 28 + w0];
        r2 = *(const float4*)&ws[WS_BIAS + (c0 + 2) * 28 + w0];
        r3 = *(const float4*)&ws[WS_BIAS + (c0 + 3) * 28 + w0];
        #pragma unroll
        for (int s = 0; s < 3; ++s) {
            int g = (s * 128 + c0) / 48;
            int yb = (s * 64 + g * 8) * 28 + w0;
            int wb = s * 8 * 128 + c0;
            #pragma unroll
            for (int j = 0; j < 8; ++j) {
                float4 wv = *(const float4*)&s_w[wb + j * 128];
                float4 yv = *(const float4*)&s_y[yb + j * 28];
                fma4(r0, wv.x, yv);
                fma4(r1, wv.y, yv);
                fma4(r2, wv.z, yv);
                fma4(r3, wv.w, yv);
            }
        }
        // Per-channel stat partials (mask w >= 25; only the wt==6 tile is partial)
        float4 rr[4] = {r0, r1, r2, r3};
        #pragma unroll
        for (int a = 0; a < 4; ++a) {
            float4 v = rr[a];
            float s1, s2;
            if (w0 + 3 < 25) {
                s1 = v.x + v.y + v.z + v.w;
                s2 = v.x * v.x + v.y * v.y + v.z * v.z + v.w * v.w;
            } else {
                s1 = v.x;
                s2 = v.x * v.x;
            }
            atomicAdd(&s_stats[c0 + a], s1);
            atomicAdd(&s_stats[128 + c0 + a], s2);
        }
    }
    __syncthreads();  // all y reads done -> safe to alias s_y as result buffer

    if (active) {
        float4 rr[4] = {r0, r1, r2, r3};
        #pragma unroll
        for (int a = 0; a < 4; ++a) {
            int base = (c0 + a) * 25 + w0;
            s_y[base] = rr[a].x;
            if (w0 + 3 < 25) {
                s_y[base + 1] = rr[a].y;
                s_y[base + 2] = rr[a].z;
                s_y[base + 3] = rr[a].w;
            }
        }
    }
    __syncthreads();

    // Coalesced streamed store of the (128 x 25) result tile
    float* ob = out + (size_t)n * (COUT * TDIM * VV) + t * VV;
    for (int i = tid; i < 128 * 25; i += 256) {
        int c = i / 25, w = i % 25;
        ob[c * (TDIM * VV) + w] = s_y[i];
    }
    // One atomic pair per channel per block, striped 8 ways to cut contention
    if (tid < 128) {
        float* st = ws + WS_STATS + (bid & 7) * 256;
        atomicAdd(&st[tid], s_stats[tid]);
        atomicAdd(&st[128 + tid], s_stats[128 + tid]);
    }
}

// ---------------------------------------------------------------------------
// Finalize: fold 8 striped accumulators -> per-channel scale/shift.
// ---------------------------------------------------------------------------
__global__ void finalize_kernel(const float* __restrict__ gamma,
                                const float* __restrict__ beta,
                                float* __restrict__ ws) {
    const int c = threadIdx.x;
    if (c < 128) {
        float s = 0.0f, q = 0.0f;
        for (int k = 0; k < 8; ++k) {
            s += ws[WS_STATS + k * 256 + c];
            q += ws[WS_STATS + k * 256 + 128 + c];
        }
        const float inv = 1.0f / (float)NTV;
        float mean = s * inv;
        float var = q * inv - mean * mean;
        float sc = gamma[c] * rsqrtf(var + 1e-5f);
        ws[WS_SCALE + c] = sc;
        ws[WS_SHIFT + c] = beta[c] - mean * sc;
    }
}

// ---------------------------------------------------------------------------
// Normalize d_out in place (float4 grid-stride; c-plane stride 6400 % 4 == 0
// so a float4 never crosses a channel boundary).
// ---------------------------------------------------------------------------
__global__ __launch_bounds__(256)
void norm_kernel(float* __restrict__ out, const float* __restrict__ ws) {
    const int total4 = OUT_TOTAL / 4;  // 13107200
    const int stride = gridDim.x * blockDim.x;
    for (int i = blockIdx.x * blockDim.x + threadIdx.x; i < total4; i += stride) {
        int c = (i / 1600) & 127;
        float sc = ws[WS_SCALE + c];
        float sh = ws[WS_SHIFT + c];
        float4 v = ((float4*)out)[i];
        v.x = fmaf(v.x, sc, sh);
        v.y = fmaf(v.y, sc, sh);
        v.z = fmaf(v.z, sc, sh);
        v.w = fmaf(v.w, sc, sh);
        ((float4*)out)[i] = v;
    }
}

extern "C" void kernel_launch(void* const* d_in, const int* in_sizes, int n_in,
                              void* d_out, int out_size, void* d_ws, size_t ws_size,
                              hipStream_t stream) {
    const float* x     = (const float*)d_in[0];
    const float* A     = (const float*)d_in[1];
    const float* PA    = (const float*)d_in[2];
    const float* Wg    = (const float*)d_in[3];
    const float* bg    = (const float*)d_in[4];
    const float* gamma = (const float*)d_in[5];
    const float* beta  = (const float*)d_in[6];
    float* out = (float*)d_out;
    float* ws  = (float*)d_ws;

    prep_kernel<<<1, 256, 0, stream>>>(A, PA, Wg, bg, ws);
    main_kernel<<<NB * TDIM, 256, 0, stream>>>(x, ws, out);
    finalize_kernel<<<1, 128, 0, stream>>>(gamma, beta, ws);
    norm_kernel<<<4096, 256, 0, stream>>>(out, ws);
}

// Round 2
// 1440.531 us; speedup vs baseline: 1.4026x; 1.4026x over previous
//
#include <hip/hip_runtime.h>
#include <math.h>

// Problem constants
#define NB   64
#define CIN  64
#define TDIM 256
#define VV   25
#define SS   3
#define COUT 128
#define NTV  (NB * TDIM * VV)              // 409600 elements per channel
#define OUT_TOTAL (NB * COUT * TDIM * VV)  // 52428800
#define TT   8                              // t per block
#define NTILE (TDIM / TT)                   // 32 t-tiles

// Workspace float offsets
#define WS_STATS 0        // 8 copies x (128 sum + 128 sumsq) = 2048 floats
#define WS_AE2   2048     // [25][84]: Aeff[s][v][w] laid out ae[v*84 + s*28 + w]
#define WS_W2    4160     // [24][128]: W2[(s*8+j)*128 + c] = Wg[(s*128+c)*8 + j]
#define WS_BIAS  7232     // [128][28]: bias_eff[c][w]
#define WS_SCALE 10816    // [128]
#define WS_SHIFT 10944    // [128]
#define WS_TOTAL 11072    // floats (44.3 KB)

__device__ __forceinline__ void fma4(float4& a, float s, const float4& b) {
    a.x = fmaf(s, b.x, a.x);
    a.y = fmaf(s, b.y, a.y);
    a.z = fmaf(s, b.z, a.z);
    a.w = fmaf(s, b.w, a.w);
}

// ---------------------------------------------------------------------------
// Prep: build Aeff / W2 / bias_eff tables in ws, zero the stats accumulators.
// ---------------------------------------------------------------------------
__global__ void prep_kernel(const float* __restrict__ A, const float* __restrict__ PA,
                            const float* __restrict__ Wg, const float* __restrict__ bg,
                            float* __restrict__ ws) {
    const int tid = threadIdx.x;
    for (int i = tid; i < 2048; i += 256) ws[WS_STATS + i] = 0.0f;
    for (int i = tid; i < 25 * 84; i += 256) {
        int v = i / 84, r = i % 84;
        int s = r / 28, w = r % 28;
        float val = 0.0f;
        if (w < 25) {
            int idx = s * 625 + v * 25 + w;
            val = A[idx] + PA[idx];
        }
        ws[WS_AE2 + i] = val;
    }
    for (int i = tid; i < 24 * 128; i += 256) {
        int row = i / 128, c = i % 128;
        int s = row / 8, j = row % 8;
        ws[WS_W2 + i] = Wg[(s * 128 + c) * 8 + j];
    }
    for (int i = tid; i < 128 * 28; i += 256) {
        int c = i / 28, w = i % 28;
        float val = 0.0f;
        if (w < 25) {
            for (int s = 0; s < 3; ++s) {
                float cs = 0.0f;
                for (int v = 0; v < 25; ++v) {
                    int idx = s * 625 + v * 25 + w;
                    cs += A[idx] + PA[idx];
                }
                val += bg[s * 128 + c] * cs;
            }
        }
        ws[WS_BIAS + i] = val;
    }
}

// ---------------------------------------------------------------------------
// Main: one block per (n, 8-t tile). XCD-aware t mapping: xcd=bid&7 owns
// t in [xcd*32, xcd*32+32) so partially-written output cache lines merge in
// ONE XCD's L2 instead of RFO ping-pong across non-coherent L2s (round-1
// showed 18x HBM write amplification from cross-XCD partial-line writes).
// ---------------------------------------------------------------------------
__global__ __launch_bounds__(256, 3)
void main_kernel(const float* __restrict__ x, float* __restrict__ ws,
                 float* __restrict__ out) {
    // LDS: 1700 + 2100 + 3072 + 5376 + 256 = 12504 floats = 50,016 B -> 3 blk/CU
    __shared__ __align__(16) float s_x[25 * 68];    // xst[v][cin], pad 68
    __shared__ __align__(16) float s_ae[25 * 84];   // ae[v][s*28+w]
    __shared__ __align__(16) float s_w[24 * 128];   // W2[(s*8+j)][c]
    __shared__ __align__(16) float s_y[3 * 64 * 28];// y[s][cin][w28]; aliased res[128*25]
    __shared__ float s_stats[256];                  // 128 sum + 128 sumsq

    const int tid = threadIdx.x;
    const int bid = blockIdx.x;
    const int xcd   = bid & 7;           // dispatch round-robin heuristic
    const int j     = bid >> 3;          // [0,256)
    const int ttile = xcd * 4 + (j & 3); // [0,32): XCD k owns t-tiles [4k,4k+4)
    const int n     = j >> 2;            // [0,64)
    const int t0    = ttile * TT;

    s_stats[tid] = 0.0f;
    for (int i = tid; i < 25 * 84; i += 256) s_ae[i] = ws[WS_AE2 + i];
    for (int i = tid; i < 24 * 128; i += 256) s_w[i] = ws[WS_W2 + i];

    // Stage-3 task assignment is fixed across the t-loop: preload bias into
    // registers, accumulate BN stats in registers.
    const bool active = tid < 224;
    int c0 = 0, w0 = 0;
    float4 b0 = {0,0,0,0}, b1 = b0, b2 = b0, b3 = b0;
    if (active) {
        int ct = tid & 31, wt = tid >> 5;
        c0 = ct * 4;
        w0 = wt * 4;
        b0 = *(const float4*)&ws[WS_BIAS + (c0 + 0) * 28 + w0];
        b1 = *(const float4*)&ws[WS_BIAS + (c0 + 1) * 28 + w0];
        b2 = *(const float4*)&ws[WS_BIAS + (c0 + 2) * 28 + w0];
        b3 = *(const float4*)&ws[WS_BIAS + (c0 + 3) * 28 + w0];
    }
    float st1[4] = {0, 0, 0, 0};
    float st2[4] = {0, 0, 0, 0};

    const float* xbase = x + (size_t)n * (CIN * TDIM * VV);
    float* obase = out + (size_t)n * (COUT * TDIM * VV);

    for (int tt = 0; tt < TT; ++tt) {
        const int t = t0 + tt;
        // Stage x[n,:,t,:] -> s_x[v*68 + cin]
        const float* xb = xbase + t * VV;
        for (int i = tid; i < 64 * 25; i += 256) {
            int cin = i / 25, v = i % 25;
            s_x[v * 68 + cin] = xb[cin * (TDIM * VV) + v];
        }
        __syncthreads();  // s_x ready; also: prev-iter store (s_y reads) done

        // Stage 2: y[s][cin][w] = sum_v x[cin][v] * Aeff[s][v][w]
        for (int task = tid; task < 336; task += 256) {
            int cint = task & 15, swt = task >> 4;
            int cin0 = cint * 4, sw0 = swt * 4;
            float4 a0 = {0, 0, 0, 0}, a1 = a0, a2 = a0, a3 = a0;
            #pragma unroll
            for (int v = 0; v < 25; ++v) {
                float4 xv = *(const float4*)&s_x[v * 68 + cin0];
                float4 av = *(const float4*)&s_ae[v * 84 + sw0];
                fma4(a0, xv.x, av);
                fma4(a1, xv.y, av);
                fma4(a2, xv.z, av);
                fma4(a3, xv.w, av);
            }
            int s = sw0 / 28, w = sw0 % 28;
            int yb = (s * 64 + cin0) * 28 + w;
            *(float4*)&s_y[yb]      = a0;
            *(float4*)&s_y[yb + 28] = a1;
            *(float4*)&s_y[yb + 56] = a2;
            *(float4*)&s_y[yb + 84] = a3;
        }
        __syncthreads();

        // Stage 3: total[c][w] = bias + sum_s sum_j W2[s8+j][c]*y[s][g*8+j][w]
        float4 r0, r1, r2, r3;
        if (active) {
            r0 = b0; r1 = b1; r2 = b2; r3 = b3;
            #pragma unroll
            for (int s = 0; s < 3; ++s) {
                int g = (s * 128 + c0) / 48;
                int yb = (s * 64 + g * 8) * 28 + w0;
                int wb = s * 8 * 128 + c0;
                #pragma unroll
                for (int jj = 0; jj < 8; ++jj) {
                    float4 wv = *(const float4*)&s_w[wb + jj * 128];
                    float4 yv = *(const float4*)&s_y[yb + jj * 28];
                    fma4(r0, wv.x, yv);
                    fma4(r1, wv.y, yv);
                    fma4(r2, wv.z, yv);
                    fma4(r3, wv.w, yv);
                }
            }
            // BN stat partials in registers (mask w >= 25)
            float4 rr[4] = {r0, r1, r2, r3};
            #pragma unroll
            for (int a = 0; a < 4; ++a) {
                float4 v = rr[a];
                if (w0 + 3 < 25) {
                    st1[a] += v.x + v.y + v.z + v.w;
                    st2[a] += v.x * v.x + v.y * v.y + v.z * v.z + v.w * v.w;
                } else {
                    st1[a] += v.x;
                    st2[a] += v.x * v.x;
                }
            }
        }
        __syncthreads();  // all s_y reads done -> safe to alias as result

        if (active) {
            float4 rr[4] = {r0, r1, r2, r3};
            #pragma unroll
            for (int a = 0; a < 4; ++a) {
                int base = (c0 + a) * 25 + w0;
                s_y[base] = rr[a].x;
                if (w0 + 3 < 25) {
                    s_y[base + 1] = rr[a].y;
                    s_y[base + 2] = rr[a].z;
                    s_y[base + 3] = rr[a].w;
                }
            }
        }
        __syncthreads();

        // Streamed store of this t's (128 x 25) tile
        float* ob = obase + t * VV;
        for (int i = tid; i < 128 * 25; i += 256) {
            int c = i / 25, w = i % 25;
            ob[c * (TDIM * VV) + w] = s_y[i];
        }
    }

    // Fold register stats -> LDS -> one striped global atomic set per block
    if (active) {
        #pragma unroll
        for (int a = 0; a < 4; ++a) {
            atomicAdd(&s_stats[c0 + a], st1[a]);
            atomicAdd(&s_stats[128 + c0 + a], st2[a]);
        }
    }
    __syncthreads();
    if (tid < 128) {
        float* st = ws + WS_STATS + xcd * 256;
        atomicAdd(&st[tid], s_stats[tid]);
        atomicAdd(&st[128 + tid], s_stats[128 + tid]);
    }
}

// ---------------------------------------------------------------------------
// Finalize: fold 8 striped accumulators -> per-channel scale/shift.
// ---------------------------------------------------------------------------
__global__ void finalize_kernel(const float* __restrict__ gamma,
                                const float* __restrict__ beta,
                                float* __restrict__ ws) {
    const int c = threadIdx.x;
    if (c < 128) {
        float s = 0.0f, q = 0.0f;
        for (int k = 0; k < 8; ++k) {
            s += ws[WS_STATS + k * 256 + c];
            q += ws[WS_STATS + k * 256 + 128 + c];
        }
        const float inv = 1.0f / (float)NTV;
        float mean = s * inv;
        float var = q * inv - mean * mean;
        float sc = gamma[c] * rsqrtf(var + 1e-5f);
        ws[WS_SCALE + c] = sc;
        ws[WS_SHIFT + c] = beta[c] - mean * sc;
    }
}

// ---------------------------------------------------------------------------
// Normalize d_out in place (float4 grid-stride; c-plane stride 6400 % 4 == 0).
// ---------------------------------------------------------------------------
__global__ __launch_bounds__(256)
void norm_kernel(float* __restrict__ out, const float* __restrict__ ws) {
    const int total4 = OUT_TOTAL / 4;  // 13107200
    const int stride = gridDim.x * blockDim.x;
    for (int i = blockIdx.x * blockDim.x + threadIdx.x; i < total4; i += stride) {
        int c = (i / 1600) & 127;
        float sc = ws[WS_SCALE + c];
        float sh = ws[WS_SHIFT + c];
        float4 v = ((float4*)out)[i];
        v.x = fmaf(v.x, sc, sh);
        v.y = fmaf(v.y, sc, sh);
        v.z = fmaf(v.z, sc, sh);
        v.w = fmaf(v.w, sc, sh);
        ((float4*)out)[i] = v;
    }
}

extern "C" void kernel_launch(void* const* d_in, const int* in_sizes, int n_in,
                              void* d_out, int out_size, void* d_ws, size_t ws_size,
                              hipStream_t stream) {
    const float* x     = (const float*)d_in[0];
    const float* A     = (const float*)d_in[1];
    const float* PA    = (const float*)d_in[2];
    const float* Wg    = (const float*)d_in[3];
    const float* bg    = (const float*)d_in[4];
    const float* gamma = (const float*)d_in[5];
    const float* beta  = (const float*)d_in[6];
    float* out = (float*)d_out;
    float* ws  = (float*)d_ws;

    prep_kernel<<<1, 256, 0, stream>>>(A, PA, Wg, bg, ws);
    main_kernel<<<NB * NTILE, 256, 0, stream>>>(x, ws, out);
    finalize_kernel<<<1, 128, 0, stream>>>(gamma, beta, ws);
    norm_kernel<<<4096, 256, 0, stream>>>(out, ws);
}

// Round 3
// 1249.949 us; speedup vs baseline: 1.6165x; 1.1525x over previous
//
#include <hip/hip_runtime.h>
#include <math.h>

// Problem constants
#define NB   64
#define CIN  64
#define TDIM 256
#define VV   25
#define SS   3
#define COUT 128
#define NTV  (NB * TDIM * VV)              // 409600 elements per channel
#define OUT_TOTAL (NB * COUT * TDIM * VV)  // 52428800
#define TT   8                              // t per block
#define NTILE (TDIM / TT)                   // 32 t-tiles

// Workspace float offsets
#define WS_STATS 0        // 8 copies x (128 sum + 128 sumsq) = 2048 floats
#define WS_AE2   2048     // [25][84]: Aeff[s][v][w] laid out ae[v*84 + s*28 + w]
#define WS_W2    4160     // [24][128]: W2[(s*8+j)*128 + c] = Wg[(s*128+c)*8 + j]
#define WS_BIAS  7232     // [128][28]: bias_eff[c][w]
#define WS_SCALE 10816    // [128]
#define WS_SHIFT 10944    // [128]
#define MID_OFF  16384    // permuted intermediate: [n][ttile][tt][c*25+v], 52428800 floats

__device__ __forceinline__ void fma4(float4& a, float s, const float4& b) {
    a.x = fmaf(s, b.x, a.x);
    a.y = fmaf(s, b.y, a.y);
    a.z = fmaf(s, b.z, a.z);
    a.w = fmaf(s, b.w, a.w);
}

// ---------------------------------------------------------------------------
// Prep: build Aeff / W2 / bias_eff tables in ws, zero the stats accumulators.
// ---------------------------------------------------------------------------
__global__ void prep_kernel(const float* __restrict__ A, const float* __restrict__ PA,
                            const float* __restrict__ Wg, const float* __restrict__ bg,
                            float* __restrict__ ws) {
    const int tid = threadIdx.x;
    for (int i = tid; i < 2048; i += 256) ws[WS_STATS + i] = 0.0f;
    for (int i = tid; i < 25 * 84; i += 256) {
        int v = i / 84, r = i % 84;
        int s = r / 28, w = r % 28;
        float val = 0.0f;
        if (w < 25) {
            int idx = s * 625 + v * 25 + w;
            val = A[idx] + PA[idx];
        }
        ws[WS_AE2 + i] = val;
    }
    for (int i = tid; i < 24 * 128; i += 256) {
        int row = i / 128, c = i % 128;
        int s = row / 8, j = row % 8;
        ws[WS_W2 + i] = Wg[(s * 128 + c) * 8 + j];
    }
    for (int i = tid; i < 128 * 28; i += 256) {
        int c = i / 28, w = i % 28;
        float val = 0.0f;
        if (w < 25) {
            for (int s = 0; s < 3; ++s) {
                float cs = 0.0f;
                for (int v = 0; v < 25; ++v) {
                    int idx = s * 625 + v * 25 + w;
                    cs += A[idx] + PA[idx];
                }
                val += bg[s * 128 + c] * cs;
            }
        }
        ws[WS_BIAS + i] = val;
    }
}

// ---------------------------------------------------------------------------
// Main: one block per (n, 8-t tile). PERM=true writes the unnormalized total
// to a contiguous permuted intermediate (zero partial-line RFO); PERM=false
// falls back to direct final-layout stores (round-2 behavior).
// ---------------------------------------------------------------------------
template <bool PERM>
__global__ __launch_bounds__(256, 3)
void main_kernel(const float* __restrict__ x, float* __restrict__ ws,
                 float* __restrict__ out, float* __restrict__ mid) {
    __shared__ __align__(16) float s_x[25 * 68];    // xst[v][cin], pad 68
    __shared__ __align__(16) float s_ae[25 * 84];   // ae[v][s*28+w]
    __shared__ __align__(16) float s_w[24 * 128];   // W2[(s*8+j)][c]
    __shared__ __align__(16) float s_y[3 * 64 * 28];// y[s][cin][w28]; aliased res[128*25]
    __shared__ float s_stats[256];                  // 128 sum + 128 sumsq

    const int tid = threadIdx.x;
    const int bid = blockIdx.x;
    const int xcd   = bid & 7;           // dispatch round-robin heuristic
    const int j     = bid >> 3;          // [0,256)
    const int ttile = xcd * 4 + (j & 3); // [0,32): XCD k owns t-tiles [4k,4k+4)
    const int n     = j >> 2;            // [0,64)
    const int t0    = ttile * TT;

    s_stats[tid] = 0.0f;
    for (int i = tid; i < 25 * 84; i += 256) s_ae[i] = ws[WS_AE2 + i];
    for (int i = tid; i < 24 * 128; i += 256) s_w[i] = ws[WS_W2 + i];

    const bool active = tid < 224;
    int c0 = 0, w0 = 0;
    float4 b0 = {0,0,0,0}, b1 = b0, b2 = b0, b3 = b0;
    if (active) {
        int ct = tid & 31, wt = tid >> 5;
        c0 = ct * 4;
        w0 = wt * 4;
        b0 = *(const float4*)&ws[WS_BIAS + (c0 + 0) * 28 + w0];
        b1 = *(const float4*)&ws[WS_BIAS + (c0 + 1) * 28 + w0];
        b2 = *(const float4*)&ws[WS_BIAS + (c0 + 2) * 28 + w0];
        b3 = *(const float4*)&ws[WS_BIAS + (c0 + 3) * 28 + w0];
    }
    float st1[4] = {0, 0, 0, 0};
    float st2[4] = {0, 0, 0, 0};

    const float* xbase = x + (size_t)n * (CIN * TDIM * VV);
    float* obase = out + (size_t)n * (COUT * TDIM * VV);
    float* mbase = mid + ((size_t)n * NTILE + ttile) * (TT * COUT * VV);

    for (int tt = 0; tt < TT; ++tt) {
        const int t = t0 + tt;
        const float* xb = xbase + t * VV;
        for (int i = tid; i < 64 * 25; i += 256) {
            int cin = i / 25, v = i % 25;
            s_x[v * 68 + cin] = xb[cin * (TDIM * VV) + v];
        }
        __syncthreads();  // s_x ready; prev-iter s_y copies done

        // Stage 2: y[s][cin][w] = sum_v x[cin][v] * Aeff[s][v][w]
        for (int task = tid; task < 336; task += 256) {
            int cint = task & 15, swt = task >> 4;
            int cin0 = cint * 4, sw0 = swt * 4;
            float4 a0 = {0, 0, 0, 0}, a1 = a0, a2 = a0, a3 = a0;
            #pragma unroll
            for (int v = 0; v < 25; ++v) {
                float4 xv = *(const float4*)&s_x[v * 68 + cin0];
                float4 av = *(const float4*)&s_ae[v * 84 + sw0];
                fma4(a0, xv.x, av);
                fma4(a1, xv.y, av);
                fma4(a2, xv.z, av);
                fma4(a3, xv.w, av);
            }
            int s = sw0 / 28, w = sw0 % 28;
            int yb = (s * 64 + cin0) * 28 + w;
            *(float4*)&s_y[yb]      = a0;
            *(float4*)&s_y[yb + 28] = a1;
            *(float4*)&s_y[yb + 56] = a2;
            *(float4*)&s_y[yb + 84] = a3;
        }
        __syncthreads();

        // Stage 3: total[c][w] = bias + sum_s sum_j W2[s8+j][c]*y[s][g*8+j][w]
        float4 r0, r1, r2, r3;
        if (active) {
            r0 = b0; r1 = b1; r2 = b2; r3 = b3;
            #pragma unroll
            for (int s = 0; s < 3; ++s) {
                int g = (s * 128 + c0) / 48;
                int yb = (s * 64 + g * 8) * 28 + w0;
                int wb = s * 8 * 128 + c0;
                #pragma unroll
                for (int jj = 0; jj < 8; ++jj) {
                    float4 wv = *(const float4*)&s_w[wb + jj * 128];
                    float4 yv = *(const float4*)&s_y[yb + jj * 28];
                    fma4(r0, wv.x, yv);
                    fma4(r1, wv.y, yv);
                    fma4(r2, wv.z, yv);
                    fma4(r3, wv.w, yv);
                }
            }
            float4 rr[4] = {r0, r1, r2, r3};
            #pragma unroll
            for (int a = 0; a < 4; ++a) {
                float4 v = rr[a];
                if (w0 + 3 < 25) {
                    st1[a] += v.x + v.y + v.z + v.w;
                    st2[a] += v.x * v.x + v.y * v.y + v.z * v.z + v.w * v.w;
                } else {
                    st1[a] += v.x;
                    st2[a] += v.x * v.x;
                }
            }
        }
        __syncthreads();  // all s_y reads done -> safe to alias as result

        if (active) {
            float4 rr[4] = {r0, r1, r2, r3};
            #pragma unroll
            for (int a = 0; a < 4; ++a) {
                int base = (c0 + a) * 25 + w0;
                s_y[base] = rr[a].x;
                if (w0 + 3 < 25) {
                    s_y[base + 1] = rr[a].y;
                    s_y[base + 2] = rr[a].z;
                    s_y[base + 3] = rr[a].w;
                }
            }
        }
        __syncthreads();

        if (PERM) {
            // Fully contiguous, 16B-aligned 12.8 KB stream per t -> no RFO
            float4* mb = (float4*)(mbase + tt * (COUT * VV));
            const float4* sy = (const float4*)s_y;
            for (int i = tid; i < 128 * 25 / 4; i += 256) mb[i] = sy[i];
        } else {
            float* ob = obase + t * VV;
            for (int i = tid; i < 128 * 25; i += 256) {
                int c = i / 25, w = i % 25;
                ob[c * (TDIM * VV) + w] = s_y[i];
            }
        }
    }

    if (active) {
        #pragma unroll
        for (int a = 0; a < 4; ++a) {
            atomicAdd(&s_stats[c0 + a], st1[a]);
            atomicAdd(&s_stats[128 + c0 + a], st2[a]);
        }
    }
    __syncthreads();
    if (tid < 128) {
        float* st = ws + WS_STATS + xcd * 256;
        atomicAdd(&st[tid], s_stats[tid]);
        atomicAdd(&st[128 + tid], s_stats[128 + tid]);
    }
}

// ---------------------------------------------------------------------------
// Finalize: fold 8 striped accumulators -> per-channel scale/shift.
// ---------------------------------------------------------------------------
__global__ void finalize_kernel(const float* __restrict__ gamma,
                                const float* __restrict__ beta,
                                float* __restrict__ ws) {
    const int c = threadIdx.x;
    if (c < 128) {
        float s = 0.0f, q = 0.0f;
        for (int k = 0; k < 8; ++k) {
            s += ws[WS_STATS + k * 256 + c];
            q += ws[WS_STATS + k * 256 + 128 + c];
        }
        const float inv = 1.0f / (float)NTV;
        float mean = s * inv;
        float var = q * inv - mean * mean;
        float sc = gamma[c] * rsqrtf(var + 1e-5f);
        ws[WS_SCALE + c] = sc;
        ws[WS_SHIFT + c] = beta[c] - mean * sc;
    }
}

// ---------------------------------------------------------------------------
// norm_perm: fused BN-apply + layout transpose. One block per (n,c):
// gathers 100B chunks from the (L3-resident) permuted mid, writes the final
// 25.6 KB (n,c)-plane as a perfectly contiguous coalesced stream.
// ---------------------------------------------------------------------------
__global__ __launch_bounds__(256)
void norm_perm(const float* __restrict__ mid, float* __restrict__ out,
               const float* __restrict__ ws) {
    const int bid = blockIdx.x;
    const int n = bid >> 7;
    const int c = bid & 127;
    const float sc = ws[WS_SCALE + c];
    const float sh = ws[WS_SHIFT + c];
    float* ob = out + ((size_t)n * COUT + c) * (TDIM * VV);
    const float* mb = mid + (size_t)n * (TDIM * COUT * VV) + c * VV;
    const int tid = threadIdx.x;
    #pragma unroll
    for (int k = 0; k < 25; ++k) {           // 25*256 == 6400 exactly
        int i = k * 256 + tid;               // linear t*25+v
        int t = i / 25, v = i - t * 25;      // t = ttile*8+tt
        float val = mb[(size_t)t * (COUT * VV) + v];
        ob[i] = fmaf(val, sc, sh);
    }
}

// ---------------------------------------------------------------------------
// Fallback: normalize d_out in place (round-2 path, used if ws too small).
// ---------------------------------------------------------------------------
__global__ __launch_bounds__(256)
void norm_inplace(float* __restrict__ out, const float* __restrict__ ws) {
    const int total4 = OUT_TOTAL / 4;
    const int stride = gridDim.x * blockDim.x;
    for (int i = blockIdx.x * blockDim.x + threadIdx.x; i < total4; i += stride) {
        int c = (i / 1600) & 127;
        float sc = ws[WS_SCALE + c];
        float sh = ws[WS_SHIFT + c];
        float4 v = ((float4*)out)[i];
        v.x = fmaf(v.x, sc, sh);
        v.y = fmaf(v.y, sc, sh);
        v.z = fmaf(v.z, sc, sh);
        v.w = fmaf(v.w, sc, sh);
        ((float4*)out)[i] = v;
    }
}

extern "C" void kernel_launch(void* const* d_in, const int* in_sizes, int n_in,
                              void* d_out, int out_size, void* d_ws, size_t ws_size,
                              hipStream_t stream) {
    const float* x     = (const float*)d_in[0];
    const float* A     = (const float*)d_in[1];
    const float* PA    = (const float*)d_in[2];
    const float* Wg    = (const float*)d_in[3];
    const float* bg    = (const float*)d_in[4];
    const float* gamma = (const float*)d_in[5];
    const float* beta  = (const float*)d_in[6];
    float* out = (float*)d_out;
    float* ws  = (float*)d_ws;
    float* mid = ws + MID_OFF;

    // ws_size is constant across calls -> deterministic branch, graph-safe.
    const bool perm = ws_size >= ((size_t)MID_OFF + (size_t)OUT_TOTAL) * sizeof(float);

    prep_kernel<<<1, 256, 0, stream>>>(A, PA, Wg, bg, ws);
    if (perm) {
        main_kernel<true><<<NB * NTILE, 256, 0, stream>>>(x, ws, out, mid);
        finalize_kernel<<<1, 128, 0, stream>>>(gamma, beta, ws);
        norm_perm<<<NB * COUT, 256, 0, stream>>>(mid, out, ws);
    } else {
        main_kernel<false><<<NB * NTILE, 256, 0, stream>>>(x, ws, out, mid);
        finalize_kernel<<<1, 128, 0, stream>>>(gamma, beta, ws);
        norm_inplace<<<4096, 256, 0, stream>>>(out, ws);
    }
}